// Round 1
// baseline (78.865 us; speedup 1.0000x reference)
//
#include <hip/hip_runtime.h>

#define IN_F 4096
#define OUT_F 4096
#define MTOK 1024   // 2*512 tokens
#define RANK 16
#define GROUP 128

typedef short bf16x8 __attribute__((ext_vector_type(8)));
typedef float f32x4 __attribute__((ext_vector_type(4)));

__device__ __forceinline__ unsigned short f2bf(float f) {
  unsigned int u = __float_as_uint(f);
  u += 0x7fff + ((u >> 16) & 1);   // round-to-nearest-even
  return (unsigned short)(u >> 16);
}

// ---------------- kernel 1: W_q = fake_quant(w0 + lora_b @ lora_a) -> bf16 ----------------
// 256 threads/block; each thread: 4 contiguous cols x 8 rows (lora_a regs reused across rows)
#define QROWS 8
__global__ __launch_bounds__(256) void quant_w(const float* __restrict__ w0,
                                               const float* __restrict__ la,
                                               const float* __restrict__ lb,
                                               const float* __restrict__ qs,
                                               unsigned short* __restrict__ wq) {
  const int bid = blockIdx.x;        // 2048 blocks: (4096/QROWS) rowgroups x 4 colblocks
  const int cb  = bid & 3;
  const int rg  = bid >> 2;
  const int i   = cb * 1024 + (threadIdx.x << 2);
  const int o0  = rg * QROWS;

  float4 areg[RANK];
  #pragma unroll
  for (int r = 0; r < RANK; ++r)
    areg[r] = *reinterpret_cast<const float4*>(&la[r * IN_F + i]);

  #pragma unroll
  for (int ro = 0; ro < QROWS; ++ro) {
    const int o = o0 + ro;
    float4 w = *reinterpret_cast<const float4*>(&w0[(size_t)o * IN_F + i]);
    const float* lbr = &lb[o * RANK];
    #pragma unroll
    for (int r = 0; r < RANK; ++r) {
      const float b = lbr[r];
      w.x = fmaf(b, areg[r].x, w.x);
      w.y = fmaf(b, areg[r].y, w.y);
      w.z = fmaf(b, areg[r].z, w.z);
      w.w = fmaf(b, areg[r].w, w.w);
    }
    const float s  = qs[o * (IN_F / GROUP) + (i >> 7)];
    const float se = s + 1e-9f;
    ushort4 ov;
    ov.x = f2bf(rintf(fminf(fmaxf(w.x / se, -8.f), 7.f)) * s);
    ov.y = f2bf(rintf(fminf(fmaxf(w.y / se, -8.f), 7.f)) * s);
    ov.z = f2bf(rintf(fminf(fmaxf(w.z / se, -8.f), 7.f)) * s);
    ov.w = f2bf(rintf(fminf(fmaxf(w.w / se, -8.f), 7.f)) * s);
    *reinterpret_cast<ushort4*>(&wq[(size_t)o * IN_F + i]) = ov;
  }
}

// ---------------- kernel 2: x f32 -> bf16 ----------------
__global__ __launch_bounds__(256) void cvt_x(const float* __restrict__ x,
                                             unsigned short* __restrict__ xb) {
  const int i = (blockIdx.x * 256 + threadIdx.x) << 2;
  float4 v = *reinterpret_cast<const float4*>(&x[i]);
  ushort4 ov;
  ov.x = f2bf(v.x); ov.y = f2bf(v.y); ov.z = f2bf(v.z); ov.w = f2bf(v.w);
  *reinterpret_cast<ushort4*>(&xb[i]) = ov;
}

// ---------------- kernel 3: C[M,N] = A[M,K] * B[N,K]^T + bias, bf16 MFMA ----------------
#define BM 64
#define BN 128
#define BK 32
#define LDS_SH ((BM + BN) * BK)   // shorts per buffer (A then B), 6144

__device__ __forceinline__ void load_lds16(const void* gsrc, void* ldst) {
  __builtin_amdgcn_global_load_lds(
      (const __attribute__((address_space(1))) unsigned int*)gsrc,
      (__attribute__((address_space(3))) unsigned int*)ldst, 16, 0, 0);
}

__global__ __launch_bounds__(256, 2) void gemm_bt(const unsigned short* __restrict__ A,
                                                  const unsigned short* __restrict__ B,
                                                  const float* __restrict__ bias,
                                                  float* __restrict__ C) {
  __shared__ unsigned short lds[2 * LDS_SH];
  const int tid  = threadIdx.x;
  const int wave = tid >> 6;
  const int lane = tid & 63;
  const int wr = wave >> 1, wc = wave & 1;     // waves 2x2; wave tile 32x64
  const int mBase = blockIdx.y * BM;
  const int nBase = blockIdx.x * BN;

  // swizzle: phys_chunk = logical_chunk ^ g(row), g(row) = (row&3) ^ ((row>>2)&1)
  auto stage = [&](int buf, int kt) {
    #pragma unroll
    for (int j = 0; j < 3; ++j) {
      const int ch = wave + j * 4;             // 12 chunks of 1KB: 0..3 = A, 4..11 = B
      const int p  = ch * 512 + lane * 8;      // phys short offset
      const int pl = (ch < 4) ? p : p - BM * BK;
      const int row = pl >> 5;                 // 32 shorts per row
      const int ccPhys = (pl >> 3) & 3;
      const int c = ccPhys ^ (row & 3) ^ ((row >> 2) & 1);
      const unsigned short* src =
          (ch < 4) ? (A + (size_t)(mBase + row) * IN_F + kt * BK + c * 8)
                   : (B + (size_t)(nBase + row) * IN_F + kt * BK + c * 8);
      load_lds16(src, &lds[buf * LDS_SH + ch * 512]);
    }
  };

  f32x4 acc[2][4];
  #pragma unroll
  for (int m = 0; m < 2; ++m)
    #pragma unroll
    for (int n = 0; n < 4; ++n)
      acc[m][n] = (f32x4){0.f, 0.f, 0.f, 0.f};

  const int r16 = lane & 15;
  const int cc  = (lane >> 4) ^ (r16 & 3) ^ ((r16 >> 2) & 1);  // swizzled k-chunk
  const int NT  = IN_F / BK;

  stage(0, 0);
  int cur = 0;
  for (int kt = 0; kt < NT; ++kt) {
    __syncthreads();                       // drains vmcnt -> stage(cur) complete
    if (kt + 1 < NT) stage(cur ^ 1, kt + 1);
    const unsigned short* Ls = &lds[cur * LDS_SH];
    bf16x8 af[2], bq[4];
    #pragma unroll
    for (int m = 0; m < 2; ++m)
      af[m] = *reinterpret_cast<const bf16x8*>(&Ls[(wr * 32 + m * 16 + r16) * BK + cc * 8]);
    #pragma unroll
    for (int n = 0; n < 4; ++n)
      bq[n] = *reinterpret_cast<const bf16x8*>(&Ls[BM * BK + (wc * 64 + n * 16 + r16) * BK + cc * 8]);
    #pragma unroll
    for (int m = 0; m < 2; ++m)
      #pragma unroll
      for (int n = 0; n < 4; ++n)
        acc[m][n] = __builtin_amdgcn_mfma_f32_16x16x32_bf16(af[m], bq[n], acc[m][n], 0, 0, 0);
    cur ^= 1;
  }

  // C/D layout: col = lane&15, row = (lane>>4)*4 + j   [m89-verified]
  #pragma unroll
  for (int m = 0; m < 2; ++m) {
    const int rowg = mBase + wr * 32 + m * 16 + (lane >> 4) * 4;
    #pragma unroll
    for (int n = 0; n < 4; ++n) {
      const int colg = nBase + wc * 64 + n * 16 + r16;
      const float bv = bias[colg];
      #pragma unroll
      for (int j = 0; j < 4; ++j)
        C[(size_t)(rowg + j) * OUT_F + colg] = acc[m][n][j] + bv;
    }
  }
}

// ---------------- fallback (only if ws too small): direct recompute ----------------
__global__ void naive_out(const float* __restrict__ x, const float* __restrict__ w0,
                          const float* __restrict__ la, const float* __restrict__ lb,
                          const float* __restrict__ qs, const float* __restrict__ bias,
                          float* __restrict__ out) {
  const int n = blockIdx.x * 256 + threadIdx.x;
  const int m = blockIdx.y;
  const float* xr = &x[(size_t)m * IN_F];
  float acc = 0.f;
  for (int kg = 0; kg < IN_F / GROUP; ++kg) {
    const float s = qs[n * (IN_F / GROUP) + kg];
    const float se = s + 1e-9f;
    for (int k0 = 0; k0 < GROUP; ++k0) {
      const int k = kg * GROUP + k0;
      float w = w0[(size_t)n * IN_F + k];
      for (int r = 0; r < RANK; ++r) w = fmaf(lb[n * RANK + r], la[r * IN_F + k], w);
      const float q = rintf(fminf(fmaxf(w / se, -8.f), 7.f));
      acc = fmaf(xr[k], q * s, acc);
    }
  }
  out[(size_t)m * OUT_F + n] = acc + bias[n];
}

extern "C" void kernel_launch(void* const* d_in, const int* in_sizes, int n_in,
                              void* d_out, int out_size, void* d_ws, size_t ws_size,
                              hipStream_t stream) {
  const float* x    = (const float*)d_in[0];
  const float* w0   = (const float*)d_in[1];
  const float* la   = (const float*)d_in[2];
  const float* lb   = (const float*)d_in[3];
  const float* qs   = (const float*)d_in[4];
  const float* bias = (const float*)d_in[5];
  float* out = (float*)d_out;

  const size_t wq_bytes = (size_t)OUT_F * IN_F * 2;
  const size_t xb_bytes = (size_t)MTOK * IN_F * 2;

  if (ws_size >= wq_bytes + xb_bytes) {
    unsigned short* wq = (unsigned short*)d_ws;
    unsigned short* xb = (unsigned short*)((char*)d_ws + wq_bytes);
    quant_w<<<(OUT_F / QROWS) * 4, 256, 0, stream>>>(w0, la, lb, qs, wq);
    cvt_x<<<(MTOK * IN_F) / 1024, 256, 0, stream>>>(x, xb);
    dim3 grid(OUT_F / BN, MTOK / BM);
    gemm_bt<<<grid, 256, 0, stream>>>(xb, wq, bias, out);
  } else {
    dim3 grid(OUT_F / 256, MTOK);
    naive_out<<<grid, 256, 0, stream>>>(x, w0, la, lb, qs, bias, out);
  }
}

// Round 4
// 66.152 us; speedup vs baseline: 1.1922x; 1.1922x over previous
//
#include <hip/hip_runtime.h>

#define IN_F 4096
#define OUT_F 4096
#define MTOK 1024   // 2*512 tokens
#define RANK 16
#define GROUP 128

typedef short bf16x8 __attribute__((ext_vector_type(8)));
typedef float f32x4 __attribute__((ext_vector_type(4)));

__device__ __forceinline__ unsigned short f2bf(float f) {
  unsigned int u = __float_as_uint(f);
  u += 0x7fff + ((u >> 16) & 1);   // round-to-nearest-even
  return (unsigned short)(u >> 16);
}

// ---------------- kernel 1: W_q = fake_quant(w0 + lora_b @ lora_a) -> bf16 ----------------
#define QROWS 8
__global__ __launch_bounds__(256) void quant_w(const float* __restrict__ w0,
                                               const float* __restrict__ la,
                                               const float* __restrict__ lb,
                                               const float* __restrict__ qs,
                                               unsigned short* __restrict__ wq) {
  const int bid = blockIdx.x;        // 2048 blocks: (4096/QROWS) rowgroups x 4 colblocks
  const int cb  = bid & 3;
  const int rg  = bid >> 2;
  const int i   = cb * 1024 + (threadIdx.x << 2);
  const int o0  = rg * QROWS;

  float4 areg[RANK];
  #pragma unroll
  for (int r = 0; r < RANK; ++r)
    areg[r] = *reinterpret_cast<const float4*>(&la[r * IN_F + i]);

  #pragma unroll
  for (int ro = 0; ro < QROWS; ++ro) {
    const int o = o0 + ro;
    float4 w = *reinterpret_cast<const float4*>(&w0[(size_t)o * IN_F + i]);
    const float* lbr = &lb[o * RANK];
    #pragma unroll
    for (int r = 0; r < RANK; ++r) {
      const float b = lbr[r];
      w.x = fmaf(b, areg[r].x, w.x);
      w.y = fmaf(b, areg[r].y, w.y);
      w.z = fmaf(b, areg[r].z, w.z);
      w.w = fmaf(b, areg[r].w, w.w);
    }
    const float s  = qs[o * (IN_F / GROUP) + (i >> 7)];
    const float se = s + 1e-9f;
    ushort4 ov;
    ov.x = f2bf(rintf(fminf(fmaxf(w.x / se, -8.f), 7.f)) * s);
    ov.y = f2bf(rintf(fminf(fmaxf(w.y / se, -8.f), 7.f)) * s);
    ov.z = f2bf(rintf(fminf(fmaxf(w.z / se, -8.f), 7.f)) * s);
    ov.w = f2bf(rintf(fminf(fmaxf(w.w / se, -8.f), 7.f)) * s);
    *reinterpret_cast<ushort4*>(&wq[(size_t)o * IN_F + i]) = ov;
  }
}

// ---------------- kernel 2: x f32 -> bf16 ----------------
__global__ __launch_bounds__(256) void cvt_x(const float* __restrict__ x,
                                             unsigned short* __restrict__ xb) {
  const int i = (blockIdx.x * 256 + threadIdx.x) << 2;
  float4 v = *reinterpret_cast<const float4*>(&x[i]);
  ushort4 ov;
  ov.x = f2bf(v.x); ov.y = f2bf(v.y); ov.z = f2bf(v.z); ov.w = f2bf(v.w);
  *reinterpret_cast<ushort4*>(&xb[i]) = ov;
}

// ---------------- kernel 3: C[M,N] = A[M,K]*B[N,K]^T + bias, bf16 MFMA ----------------
// 512 threads = 2 K-groups x 4 waves. Block tile 128x128; each group does K=2048.
// Wave tile 64x64 (4x4 frags of 16x16x32): 16 MFMA per 8 ds_read_b128.
// LDS: per group 2 buffers x (A[128][64] + B[128][64]) shorts = 64KB; total 128KB.
// Chunk swizzle: phys16Bchunk = logchunk ^ (row&7)  (applied on global src; LDS linear).
#define BM 128
#define BN 128
#define BK 64
#define KSPLIT 2
#define KHALF (IN_F / KSPLIT)   // 2048
#define NT (KHALF / BK)         // 32
#define GBUF 16384              // shorts per buffer per group

__device__ __forceinline__ void load_lds16(const void* gsrc, void* ldst) {
  __builtin_amdgcn_global_load_lds(
      (const __attribute__((address_space(1))) unsigned int*)gsrc,
      (__attribute__((address_space(3))) unsigned int*)ldst, 16, 0, 0);
}

__global__ __launch_bounds__(512, 2) void gemm_bt(const unsigned short* __restrict__ A,
                                                  const unsigned short* __restrict__ B,
                                                  const float* __restrict__ bias,
                                                  float* __restrict__ C) {
  __shared__ unsigned short lds[2 * 2 * GBUF];   // [group][buf][16384] = 128KB
  const int tid  = threadIdx.x;
  const int wave = tid >> 6;
  const int lane = tid & 63;
  const int grp  = wave >> 2;
  const int wg   = wave & 3;
  const int wr   = wg >> 1, wc = wg & 1;         // 2x2 waves over 128x128, wave tile 64x64
  const int mBase = blockIdx.y * BM;
  const int nBase = blockIdx.x * BN;
  const int r16 = lane & 15;
  const int hi  = lane >> 4;                     // k-chunk within 32-slice

  unsigned short* gl = &lds[grp * 2 * GBUF];
  const size_t kOff = (size_t)grp * KHALF;

  auto stage = [&](int buf, int kt) {
    const size_t kcol = kOff + kt * BK;
    #pragma unroll
    for (int j = 0; j < 8; ++j) {
      const int chunk = j * 256 + wg * 64 + lane;   // 0..2047 (16B units)
      const int row   = (chunk & 1023) >> 3;        // 8 chunks per 64-short row
      const int cph   = chunk & 7;
      const int clog  = cph ^ (row & 7);
      const unsigned short* src = (chunk >> 10)
          ? (B + (size_t)(nBase + row) * IN_F + kcol + clog * 8)
          : (A + (size_t)(mBase + row) * IN_F + kcol + clog * 8);
      load_lds16(src, &gl[buf * GBUF + (j * 256 + wg * 64) * 8]);
    }
  };

  f32x4 acc[4][4];
  #pragma unroll
  for (int m = 0; m < 4; ++m)
    #pragma unroll
    for (int n = 0; n < 4; ++n)
      acc[m][n] = (f32x4){0.f, 0.f, 0.f, 0.f};

  stage(0, 0);
  int cur = 0;
  for (int kt = 0; kt < NT; ++kt) {
    __syncthreads();                       // staged(cur) complete; cur^1 free
    if (kt + 1 < NT) stage(cur ^ 1, kt + 1);
    const unsigned short* Ls = &gl[cur * GBUF];
    const int sw = r16 & 7;
    #pragma unroll
    for (int kk = 0; kk < 2; ++kk) {
      const int ch = kk * 4 + hi;
      bf16x8 af[4], bq[4];
      #pragma unroll
      for (int m = 0; m < 4; ++m) {
        const int row = wr * 64 + m * 16 + r16;
        af[m] = *reinterpret_cast<const bf16x8*>(&Ls[row * 64 + (ch ^ sw) * 8]);
      }
      #pragma unroll
      for (int n = 0; n < 4; ++n) {
        const int row = wc * 64 + n * 16 + r16;
        bq[n] = *reinterpret_cast<const bf16x8*>(&Ls[8192 + row * 64 + (ch ^ sw) * 8]);
      }
      #pragma unroll
      for (int m = 0; m < 4; ++m)
        #pragma unroll
        for (int n = 0; n < 4; ++n)
          acc[m][n] = __builtin_amdgcn_mfma_f32_16x16x32_bf16(af[m], bq[n], acc[m][n], 0, 0, 0);
    }
    cur ^= 1;
  }

  // ---- cross-group reduce through LDS (reuse group-1's 64KB region) ----
  __syncthreads();                         // everyone done reading LDS buffers
  float* ex = reinterpret_cast<float*>(&lds[2 * GBUF]);   // 16384 floats
  if (grp == 1) {
    #pragma unroll
    for (int m = 0; m < 4; ++m)
      #pragma unroll
      for (int n = 0; n < 4; ++n)
        *reinterpret_cast<f32x4*>(&ex[wg * 4096 + (m * 4 + n) * 256 + lane * 4]) = acc[m][n];
  }
  __syncthreads();
  if (grp == 0) {
    #pragma unroll
    for (int m = 0; m < 4; ++m) {
      const int rowg = mBase + wr * 64 + m * 16 + hi * 4;
      #pragma unroll
      for (int n = 0; n < 4; ++n) {
        const f32x4 p = *reinterpret_cast<const f32x4*>(&ex[wg * 4096 + (m * 4 + n) * 256 + lane * 4]);
        const int colg = nBase + wc * 64 + n * 16 + r16;
        const float bv = bias[colg];
        #pragma unroll
        for (int j = 0; j < 4; ++j)
          C[(size_t)(rowg + j) * OUT_F + colg] = acc[m][n][j] + p[j] + bv;
      }
    }
  }
}

// ---------------- fallback (only if ws too small): direct recompute ----------------
__global__ void naive_out(const float* __restrict__ x, const float* __restrict__ w0,
                          const float* __restrict__ la, const float* __restrict__ lb,
                          const float* __restrict__ qs, const float* __restrict__ bias,
                          float* __restrict__ out) {
  const int n = blockIdx.x * 256 + threadIdx.x;
  const int m = blockIdx.y;
  const float* xr = &x[(size_t)m * IN_F];
  float acc = 0.f;
  for (int kg = 0; kg < IN_F / GROUP; ++kg) {
    const float s = qs[n * (IN_F / GROUP) + kg];
    const float se = s + 1e-9f;
    for (int k0 = 0; k0 < GROUP; ++k0) {
      const int k = kg * GROUP + k0;
      float w = w0[(size_t)n * IN_F + k];
      for (int r = 0; r < RANK; ++r) w = fmaf(lb[n * RANK + r], la[r * IN_F + k], w);
      const float q = rintf(fminf(fmaxf(w / se, -8.f), 7.f));
      acc = fmaf(xr[k], q * s, acc);
    }
  }
  out[(size_t)m * OUT_F + n] = acc + bias[n];
}

extern "C" void kernel_launch(void* const* d_in, const int* in_sizes, int n_in,
                              void* d_out, int out_size, void* d_ws, size_t ws_size,
                              hipStream_t stream) {
  const float* x    = (const float*)d_in[0];
  const float* w0   = (const float*)d_in[1];
  const float* la   = (const float*)d_in[2];
  const float* lb   = (const float*)d_in[3];
  const float* qs   = (const float*)d_in[4];
  const float* bias = (const float*)d_in[5];
  float* out = (float*)d_out;

  const size_t wq_bytes = (size_t)OUT_F * IN_F * 2;
  const size_t xb_bytes = (size_t)MTOK * IN_F * 2;

  if (ws_size >= wq_bytes + xb_bytes) {
    unsigned short* wq = (unsigned short*)d_ws;
    unsigned short* xb = (unsigned short*)((char*)d_ws + wq_bytes);
    quant_w<<<(OUT_F / QROWS) * 4, 256, 0, stream>>>(w0, la, lb, qs, wq);
    cvt_x<<<(MTOK * IN_F) / 1024, 256, 0, stream>>>(x, xb);
    dim3 grid(OUT_F / BN, MTOK / BM);
    gemm_bt<<<grid, 512, 0, stream>>>(xb, wq, bias, out);
  } else {
    dim3 grid(OUT_F / 256, MTOK);
    naive_out<<<grid, 256, 0, stream>>>(x, w0, la, lb, qs, bias, out);
  }
}